// Round 1
// baseline (179.031 us; speedup 1.0000x reference)
//
#include <hip/hip_runtime.h>
#include <math.h>

// ---------------------------------------------------------------------------
// TwoSimplicialAttention, MI355X. Structure exploit: mask kills attention for
// all s < 2016; only last 32 rows/batch (64 rows) carry attention. Everything
// else is out = LayerNorm(x).
// ---------------------------------------------------------------------------

#define XS 68   // LDS leading-dim pad (68 floats = 17x16B: b128-aligned rows)

// workspace layout (floats)
#define YQ_OFF    0         // 64 x 1024  q projections (window rows)
#define YK_OFF    65536     // 64 x 1024  k
#define YKP_OFF   131072    // 64 x 1024  kp
#define YV_OFF    196608    // 64 x 1024  v
#define Z_OFF     262144    // 64 x 1024  attention output rows
#define DELTA_OFF 327680    // 64 x 1024  Z @ W_O
#define WS_FLOATS 393216    // 1.5 MB

__global__ __launch_bounds__(256) void zero_ws(float4* __restrict__ ws) {
  ws[blockIdx.x * 256 + threadIdx.x] = make_float4(0.f, 0.f, 0.f, 0.f);
}

// ---- kernel A: Y[64][4096] = x_win @ [W_Q | W_K | W_Kp | W_V] -------------
// grid (4 colblocks, 16 ksplits, 4 matrices); split-k partials via atomicAdd.
// W is read exactly once from HBM, fully coalesced.
__global__ __launch_bounds__(256) void proj_kernel(
    const float* __restrict__ x,
    const float* __restrict__ Wq, const float* __restrict__ Wk,
    const float* __restrict__ Wkp, const float* __restrict__ Wv,
    float* __restrict__ Y) {
  __shared__ float xs[64 * XS];      // [kk][r]
  const int tid = threadIdx.x;
  const int col = blockIdx.x * 256 + tid;
  const int k0  = blockIdx.y * 64;
  const int z   = blockIdx.z;
  const float* W = (z == 0) ? Wq : ((z == 1) ? Wk : ((z == 2) ? Wkp : Wv));

  // stage x window rows, k-chunk [k0,k0+64)  (float4 global loads)
  #pragma unroll
  for (int i = 0; i < 4; i++) {
    int e = i * 256 + tid;           // 1024 float4 slots: r(64) x quad(16)
    int r = e >> 4, qq = e & 15;
    int b = r >> 5, t = r & 31;
    float4 v = *(const float4*)(x + ((b * 2048 + 2016 + t) * 1024 + k0 + qq * 4));
    xs[(qq * 4 + 0) * XS + r] = v.x;
    xs[(qq * 4 + 1) * XS + r] = v.y;
    xs[(qq * 4 + 2) * XS + r] = v.z;
    xs[(qq * 4 + 3) * XS + r] = v.w;
  }
  __syncthreads();

  float acc[64];
  #pragma unroll
  for (int r = 0; r < 64; r++) acc[r] = 0.f;

  float w = W[k0 * 1024 + col];
  for (int kk = 0; kk < 64; kk++) {
    float wn = (kk < 63) ? W[(k0 + kk + 1) * 1024 + col] : 0.f;  // prefetch
    const float* xr = xs + kk * XS;   // broadcast reads (ds b128 x16)
    #pragma unroll
    for (int r = 0; r < 64; r++) acc[r] += xr[r] * w;
    w = wn;
  }
  float* Yo = Y + z * 65536 + col;
  #pragma unroll
  for (int r = 0; r < 64; r++) atomicAdd(Yo + r * 1024, acc[r]);
}

// ---- kernel B: attention for the 64 window rows ---------------------------
// grid (8 s-groups, 16 heads, 2 batches), 4 waves/block, one (b,h,s) per wave.
__global__ __launch_bounds__(256) void attn_kernel(
    const float* __restrict__ Y, float* __restrict__ Zout) {
  __shared__ float Kn[32 * XS], Kp[32 * XS], Vs[32 * XS];
  __shared__ float Pt[4][32 * 33];   // exp(A)^T per wave, [k][j], pad 33
  __shared__ float qs[4][64];
  const int tid = threadIdx.x;
  const int wave = tid >> 6, lane = tid & 63;
  const int h = blockIdx.y, b = blockIdx.z;

  // stage K / Kp / V window tiles for this (b,h)
  #pragma unroll
  for (int i = 0; i < 8; i++) {
    int e = i * 256 + tid;           // 2048: row(32) x d(64)
    int row = e >> 6, d = e & 63;
    int src = (b * 32 + row) * 1024 + h * 64 + d;
    Kn[row * XS + d] = Y[YK_OFF + src];
    Kp[row * XS + d] = Y[YKP_OFF + src];
    Vs[row * XS + d] = Y[YV_OFF + src];
  }
  __syncthreads();

  // l2-normalize K, Kp rows (wave w handles rows 8w..8w+7; lane = d)
  for (int rr = 0; rr < 8; rr++) {
    int row = wave * 8 + rr;
    float kv = Kn[row * XS + lane];
    float s2 = kv * kv;
    #pragma unroll
    for (int off = 1; off < 64; off <<= 1) s2 += __shfl_xor(s2, off);
    Kn[row * XS + lane] = kv * (1.f / (sqrtf(s2) + 1e-7f));
    float pv = Kp[row * XS + lane];
    float p2 = pv * pv;
    #pragma unroll
    for (int off = 1; off < 64; off <<= 1) p2 += __shfl_xor(p2, off);
    Kp[row * XS + lane] = pv * (1.f / (sqrtf(p2) + 1e-7f));
  }
  __syncthreads();

  const int m = blockIdx.x * 4 + wave;   // s_local = s - 2016, valid j,k <= m
  const int r = b * 32 + m;

  // q-hat (lane = d)
  float q = Y[YQ_OFF + r * 1024 + h * 64 + lane];
  float q2 = q * q;
  #pragma unroll
  for (int off = 1; off < 64; off <<= 1) q2 += __shfl_xor(q2, off);
  q *= (1.f / (sqrtf(q2) + 1e-7f));
  qs[wave][lane] = q;
  __builtin_amdgcn_wave_barrier();

  // A[j][k] = sum_d qhat[d] Khat[j][d] Kphat[k][d]; register-tiled 4x4/lane
  const int lj = lane >> 3, lk = lane & 7;
  float acc[4][4];
  #pragma unroll
  for (int a = 0; a < 4; a++)
    #pragma unroll
    for (int c = 0; c < 4; c++) acc[a][c] = 0.f;

  const float* qw = qs[wave];
  for (int dq = 0; dq < 16; dq++) {
    float4 q4 = *(const float4*)(qw + dq * 4);   // broadcast
    float4 t4[4], kp4[4];
    #pragma unroll
    for (int tj = 0; tj < 4; tj++) {
      float4 kv = *(const float4*)(Kn + (lj * 4 + tj) * XS + dq * 4);
      t4[tj].x = q4.x * kv.x; t4[tj].y = q4.y * kv.y;
      t4[tj].z = q4.z * kv.z; t4[tj].w = q4.w * kv.w;
    }
    #pragma unroll
    for (int tk = 0; tk < 4; tk++)
      kp4[tk] = *(const float4*)(Kp + (lk * 4 + tk) * XS + dq * 4);
    #pragma unroll
    for (int tj = 0; tj < 4; tj++)
      #pragma unroll
      for (int tk = 0; tk < 4; tk++)
        acc[tj][tk] += t4[tj].x * kp4[tk].x + t4[tj].y * kp4[tk].y
                     + t4[tj].z * kp4[tk].z + t4[tj].w * kp4[tk].w;
  }

  // masked softmax over valid (j<=m, k<=m); scale 1/sqrt(64)
  float amax = -1e30f;
  #pragma unroll
  for (int tj = 0; tj < 4; tj++)
    #pragma unroll
    for (int tk = 0; tk < 4; tk++) {
      int j = lj * 4 + tj, k = lk * 4 + tk;
      if (j <= m && k <= m) amax = fmaxf(amax, acc[tj][tk] * 0.125f);
    }
  #pragma unroll
  for (int off = 1; off < 64; off <<= 1) amax = fmaxf(amax, __shfl_xor(amax, off));

  float lsum = 0.f;
  float* ptw = Pt[wave];
  #pragma unroll
  for (int tj = 0; tj < 4; tj++)
    #pragma unroll
    for (int tk = 0; tk < 4; tk++) {
      int j = lj * 4 + tj, k = lk * 4 + tk;
      float e = 0.f;
      if (j <= m && k <= m) e = __expf(acc[tj][tk] * 0.125f - amax);
      lsum += e;
      ptw[k * 33 + j] = e;            // full 32x32 written (0 where invalid)
    }
  #pragma unroll
  for (int off = 1; off < 64; off <<= 1) lsum += __shfl_xor(lsum, off);
  float inv = 1.f / lsum;
  __builtin_amdgcn_wave_barrier();

  // Z[d] = sum_k V[k][d] * (sum_j e[j][k] V[j][d]); lane = d, V column in regs
  float vreg[32];
  #pragma unroll
  for (int k = 0; k < 32; k++) vreg[k] = Vs[k * XS + lane];
  float zacc = 0.f;
  for (int k = 0; k <= m; k++) {
    float g = 0.f;
    #pragma unroll
    for (int j = 0; j < 32; j++) g += ptw[k * 33 + j] * vreg[j];  // bcast reads
    zacc += g * vreg[k];
  }
  Zout[r * 1024 + h * 64 + lane] = zacc * inv;
}

// ---- kernel C: delta[64][1024] = Z @ W_O (split-k atomics) ----------------
__global__ __launch_bounds__(256) void wo_kernel(
    const float* __restrict__ Zr, const float* __restrict__ Wo,
    float* __restrict__ delta) {
  __shared__ float zs[32 * XS];      // [kk][r]
  const int tid = threadIdx.x;
  const int col = blockIdx.x * 256 + tid;
  const int k0  = blockIdx.y * 32;
  #pragma unroll
  for (int i = 0; i < 8; i++) {
    int e = i * 256 + tid;           // 2048: r(64) x kk(32)
    int r = e >> 5, kk = e & 31;
    zs[kk * XS + r] = Zr[r * 1024 + k0 + kk];
  }
  __syncthreads();

  float acc[64];
  #pragma unroll
  for (int r = 0; r < 64; r++) acc[r] = 0.f;

  float w = Wo[k0 * 1024 + col];
  for (int kk = 0; kk < 32; kk++) {
    float wn = (kk < 31) ? Wo[(k0 + kk + 1) * 1024 + col] : 0.f;
    const float* zrow = zs + kk * XS;
    #pragma unroll
    for (int r = 0; r < 64; r++) acc[r] += zrow[r] * w;
    w = wn;
  }
  #pragma unroll
  for (int r = 0; r < 64; r++) atomicAdd(delta + r * 1024 + col, acc[r]);
}

// ---- kernel D: out = LayerNorm(x + delta) over all 4096 rows --------------
__global__ __launch_bounds__(256) void ln_kernel(
    const float* __restrict__ x, const float* __restrict__ delta,
    const float* __restrict__ gamma, const float* __restrict__ beta,
    float* __restrict__ out) {
  const int row = blockIdx.x;        // 0..4095
  const int tid = threadIdx.x;
  const int b = row >> 11, s = row & 2047;

  float4 v = *(const float4*)(x + (size_t)row * 1024 + tid * 4);
  if (s >= 2016) {                   // block-uniform branch
    float4 dv = *(const float4*)(delta + (b * 32 + (s - 2016)) * 1024 + tid * 4);
    v.x += dv.x; v.y += dv.y; v.z += dv.z; v.w += dv.w;
  }
  float sum = v.x + v.y + v.z + v.w;
  float ss  = v.x * v.x + v.y * v.y + v.z * v.z + v.w * v.w;
  #pragma unroll
  for (int off = 1; off < 64; off <<= 1) {
    sum += __shfl_xor(sum, off);
    ss  += __shfl_xor(ss, off);
  }
  __shared__ float red[8];
  int wave = tid >> 6, lane = tid & 63;
  if (lane == 0) { red[wave] = sum; red[4 + wave] = ss; }
  __syncthreads();
  sum = red[0] + red[1] + red[2] + red[3];
  ss  = red[4] + red[5] + red[6] + red[7];
  float mu   = sum * (1.f / 1024.f);
  float var  = ss * (1.f / 1024.f) - mu * mu;
  float rstd = rsqrtf(var + 1e-5f);

  float4 g  = *(const float4*)(gamma + tid * 4);
  float4 be = *(const float4*)(beta + tid * 4);
  float4 o;
  o.x = (v.x - mu) * rstd * g.x + be.x;
  o.y = (v.y - mu) * rstd * g.y + be.y;
  o.z = (v.z - mu) * rstd * g.z + be.z;
  o.w = (v.w - mu) * rstd * g.w + be.w;
  *(float4*)(out + (size_t)row * 1024 + tid * 4) = o;
}

// ---------------------------------------------------------------------------
extern "C" void kernel_launch(void* const* d_in, const int* in_sizes, int n_in,
                              void* d_out, int out_size, void* d_ws, size_t ws_size,
                              hipStream_t stream) {
  const float* x   = (const float*)d_in[0];
  const float* Wq  = (const float*)d_in[1];
  const float* Wk  = (const float*)d_in[2];
  const float* Wv  = (const float*)d_in[3];  // NB: dict order, W_V before W_Kp
  const float* Wkp = (const float*)d_in[4];
  const float* Wo  = (const float*)d_in[5];
  const float* gam = (const float*)d_in[6];
  const float* bet = (const float*)d_in[7];
  float* out = (float*)d_out;
  float* ws  = (float*)d_ws;   // needs 1.5 MB

  hipLaunchKernelGGL(zero_ws, dim3(WS_FLOATS / 1024), dim3(256), 0, stream,
                     (float4*)ws);
  hipLaunchKernelGGL(proj_kernel, dim3(4, 16, 4), dim3(256), 0, stream,
                     x, Wq, Wk, Wkp, Wv, ws);
  hipLaunchKernelGGL(attn_kernel, dim3(8, 16, 2), dim3(256), 0, stream,
                     ws, ws + Z_OFF);
  hipLaunchKernelGGL(wo_kernel, dim3(4, 32), dim3(256), 0, stream,
                     ws + Z_OFF, Wo, ws + DELTA_OFF);
  hipLaunchKernelGGL(ln_kernel, dim3(4096), dim3(256), 0, stream,
                     x, ws + DELTA_OFF, gam, bet, out);
}

// Round 2
// 141.880 us; speedup vs baseline: 1.2618x; 1.2618x over previous
//
#include <hip/hip_runtime.h>
#include <math.h>

// ---------------------------------------------------------------------------
// TwoSimplicialAttention, MI355X. Structure exploit: mask kills attention for
// all s < 2016; only last 32 rows/batch (64 rows) carry attention. Everything
// else is out = LayerNorm(x).
//
// R2: proj/wo rewritten lane=row + W via s_load (scalar cache broadcast);
// ln rewritten one-wave-per-row (no __syncthreads).
// ---------------------------------------------------------------------------

#define XS 68   // attn LDS pad

// workspace layout (floats)
#define YQ_OFF    0         // 64 x 1024  q projections (window rows)
#define YK_OFF    65536     // 64 x 1024  k
#define YKP_OFF   131072    // 64 x 1024  kp
#define YV_OFF    196608    // 64 x 1024  v
#define Z_OFF     262144    // 64 x 1024  attention output rows
#define DELTA_OFF 327680    // 64 x 1024  Z @ W_O
#define WS_FLOATS 393216    // 1.5 MB

__global__ __launch_bounds__(256) void zero_ws(float4* __restrict__ ws) {
  ws[blockIdx.x * 256 + threadIdx.x] = make_float4(0.f, 0.f, 0.f, 0.f);
}

// ---- kernel A: Y[64][4096] = x_win @ [W_Q | W_K | W_Kp | W_V] -------------
// grid (64 colblocks of 64 cols, 16 ksplits of 64 k) = 1024 blocks.
// lane = row (64 rows), wave owns 16 cols. x: 1 ds_read_b32/k (vector read).
// W: 16 consecutive uniform floats/k -> s_load_dwordx16 via scalar cache.
__global__ __launch_bounds__(256, 4) void proj_kernel(
    const float* __restrict__ x,
    const float* __restrict__ Wq, const float* __restrict__ Wk,
    const float* __restrict__ Wkp, const float* __restrict__ Wv,
    float* __restrict__ Y) {
  __shared__ float xs[64 * 65];      // [kk][r], pad 65 (conflict-free)
  const int tid = threadIdx.x;
  const int z    = blockIdx.x >> 4;                 // which W matrix
  const int col0 = (blockIdx.x & 15) * 64;
  const int k0   = blockIdx.y * 64;
  const float* __restrict__ W =
      (z == 0) ? Wq : ((z == 1) ? Wk : ((z == 2) ? Wkp : Wv));

  // stage x^T tile: 64 rows x 64 k  (coalesced float4 reads)
  #pragma unroll
  for (int i = 0; i < 4; i++) {
    int e = i * 256 + tid;           // 1024 slots: r(64) x quad(16)
    int r = e >> 4, q = e & 15;
    int b = r >> 5, t = r & 31;
    float4 v = *(const float4*)(x + ((b * 2048 + 2016 + t) * 1024 + k0 + q * 4));
    xs[(q * 4 + 0) * 65 + r] = v.x;
    xs[(q * 4 + 1) * 65 + r] = v.y;
    xs[(q * 4 + 2) * 65 + r] = v.z;
    xs[(q * 4 + 3) * 65 + r] = v.w;
  }
  __syncthreads();

  const int wave = __builtin_amdgcn_readfirstlane(tid >> 6);  // uniform!
  const int lane = tid & 63;                                   // = row
  const float* __restrict__ Wt = W + (size_t)k0 * 1024 + col0 + wave * 16;

  float acc[16];
  #pragma unroll
  for (int c = 0; c < 16; c++) acc[c] = 0.f;

  #pragma unroll 4
  for (int kk = 0; kk < 64; kk++) {
    float xv = xs[kk * 65 + lane];               // conflict-free vector read
    const float* __restrict__ wrow = Wt + kk * 1024;  // uniform -> s_load x16
    #pragma unroll
    for (int c = 0; c < 16; c++) acc[c] = fmaf(xv, wrow[c], acc[c]);
  }

  // transpose through LDS for coalesced atomics
  __syncthreads();                   // xs reads done
  #pragma unroll
  for (int c = 0; c < 16; c++) xs[lane * 65 + wave * 16 + c] = acc[c];
  __syncthreads();
  float* __restrict__ Yo = Y + z * 65536 + col0;
  #pragma unroll
  for (int i = 0; i < 16; i++) {
    int r = wave * 16 + i;
    atomicAdd(Yo + r * 1024 + lane, xs[r * 65 + lane]);  // 64 lanes coalesced
  }
}

// ---- kernel B: attention for the 64 window rows (unchanged, correct) ------
__global__ __launch_bounds__(256) void attn_kernel(
    const float* __restrict__ Y, float* __restrict__ Zout) {
  __shared__ float Kn[32 * XS], Kp[32 * XS], Vs[32 * XS];
  __shared__ float Pt[4][32 * 33];
  __shared__ float qs[4][64];
  const int tid = threadIdx.x;
  const int wave = tid >> 6, lane = tid & 63;
  const int h = blockIdx.y, b = blockIdx.z;

  #pragma unroll
  for (int i = 0; i < 8; i++) {
    int e = i * 256 + tid;
    int row = e >> 6, d = e & 63;
    int src = (b * 32 + row) * 1024 + h * 64 + d;
    Kn[row * XS + d] = Y[YK_OFF + src];
    Kp[row * XS + d] = Y[YKP_OFF + src];
    Vs[row * XS + d] = Y[YV_OFF + src];
  }
  __syncthreads();

  for (int rr = 0; rr < 8; rr++) {
    int row = wave * 8 + rr;
    float kv = Kn[row * XS + lane];
    float s2 = kv * kv;
    #pragma unroll
    for (int off = 1; off < 64; off <<= 1) s2 += __shfl_xor(s2, off);
    Kn[row * XS + lane] = kv * (1.f / (sqrtf(s2) + 1e-7f));
    float pv = Kp[row * XS + lane];
    float p2 = pv * pv;
    #pragma unroll
    for (int off = 1; off < 64; off <<= 1) p2 += __shfl_xor(p2, off);
    Kp[row * XS + lane] = pv * (1.f / (sqrtf(p2) + 1e-7f));
  }
  __syncthreads();

  const int m = blockIdx.x * 4 + wave;
  const int r = b * 32 + m;

  float q = Y[YQ_OFF + r * 1024 + h * 64 + lane];
  float q2 = q * q;
  #pragma unroll
  for (int off = 1; off < 64; off <<= 1) q2 += __shfl_xor(q2, off);
  q *= (1.f / (sqrtf(q2) + 1e-7f));
  qs[wave][lane] = q;
  __builtin_amdgcn_wave_barrier();

  const int lj = lane >> 3, lk = lane & 7;
  float acc[4][4];
  #pragma unroll
  for (int a = 0; a < 4; a++)
    #pragma unroll
    for (int c = 0; c < 4; c++) acc[a][c] = 0.f;

  const float* qw = qs[wave];
  for (int dq = 0; dq < 16; dq++) {
    float4 q4 = *(const float4*)(qw + dq * 4);
    float4 t4[4], kp4[4];
    #pragma unroll
    for (int tj = 0; tj < 4; tj++) {
      float4 kv = *(const float4*)(Kn + (lj * 4 + tj) * XS + dq * 4);
      t4[tj].x = q4.x * kv.x; t4[tj].y = q4.y * kv.y;
      t4[tj].z = q4.z * kv.z; t4[tj].w = q4.w * kv.w;
    }
    #pragma unroll
    for (int tk = 0; tk < 4; tk++)
      kp4[tk] = *(const float4*)(Kp + (lk * 4 + tk) * XS + dq * 4);
    #pragma unroll
    for (int tj = 0; tj < 4; tj++)
      #pragma unroll
      for (int tk = 0; tk < 4; tk++)
        acc[tj][tk] += t4[tj].x * kp4[tk].x + t4[tj].y * kp4[tk].y
                     + t4[tj].z * kp4[tk].z + t4[tj].w * kp4[tk].w;
  }

  float amax = -1e30f;
  #pragma unroll
  for (int tj = 0; tj < 4; tj++)
    #pragma unroll
    for (int tk = 0; tk < 4; tk++) {
      int j = lj * 4 + tj, k = lk * 4 + tk;
      if (j <= m && k <= m) amax = fmaxf(amax, acc[tj][tk] * 0.125f);
    }
  #pragma unroll
  for (int off = 1; off < 64; off <<= 1) amax = fmaxf(amax, __shfl_xor(amax, off));

  float lsum = 0.f;
  float* ptw = Pt[wave];
  #pragma unroll
  for (int tj = 0; tj < 4; tj++)
    #pragma unroll
    for (int tk = 0; tk < 4; tk++) {
      int j = lj * 4 + tj, k = lk * 4 + tk;
      float e = 0.f;
      if (j <= m && k <= m) e = __expf(acc[tj][tk] * 0.125f - amax);
      lsum += e;
      ptw[k * 33 + j] = e;
    }
  #pragma unroll
  for (int off = 1; off < 64; off <<= 1) lsum += __shfl_xor(lsum, off);
  float inv = 1.f / lsum;
  __builtin_amdgcn_wave_barrier();

  float vreg[32];
  #pragma unroll
  for (int k = 0; k < 32; k++) vreg[k] = Vs[k * XS + lane];
  float zacc = 0.f;
  for (int k = 0; k <= m; k++) {
    float g = 0.f;
    #pragma unroll
    for (int j = 0; j < 32; j++) g += ptw[k * 33 + j] * vreg[j];
    zacc += g * vreg[k];
  }
  Zout[r * 1024 + h * 64 + lane] = zacc * inv;
}

// ---- kernel C: delta[64][1024] = Z @ W_O -- same lane=row + s_load scheme -
// grid (16 colblocks of 64 cols, 32 ksplits of 32 k) = 512 blocks.
__global__ __launch_bounds__(256, 4) void wo_kernel(
    const float* __restrict__ Zr, const float* __restrict__ Wo,
    float* __restrict__ delta) {
  __shared__ float xs[64 * 65];      // staging uses [32][65]; epilogue [64][65]
  const int tid = threadIdx.x;
  const int col0 = blockIdx.x * 64;
  const int k0   = blockIdx.y * 32;

  #pragma unroll
  for (int i = 0; i < 2; i++) {
    int e = i * 256 + tid;           // 512 slots: r(64) x quad(8)
    int r = e >> 3, q = e & 7;
    float4 v = *(const float4*)(Zr + r * 1024 + k0 + q * 4);
    xs[(q * 4 + 0) * 65 + r] = v.x;
    xs[(q * 4 + 1) * 65 + r] = v.y;
    xs[(q * 4 + 2) * 65 + r] = v.z;
    xs[(q * 4 + 3) * 65 + r] = v.w;
  }
  __syncthreads();

  const int wave = __builtin_amdgcn_readfirstlane(tid >> 6);
  const int lane = tid & 63;         // = row
  const float* __restrict__ Wt = Wo + (size_t)k0 * 1024 + col0 + wave * 16;

  float acc[16];
  #pragma unroll
  for (int c = 0; c < 16; c++) acc[c] = 0.f;

  #pragma unroll 4
  for (int kk = 0; kk < 32; kk++) {
    float xv = xs[kk * 65 + lane];
    const float* __restrict__ wrow = Wt + kk * 1024;
    #pragma unroll
    for (int c = 0; c < 16; c++) acc[c] = fmaf(xv, wrow[c], acc[c]);
  }

  __syncthreads();
  #pragma unroll
  for (int c = 0; c < 16; c++) xs[lane * 65 + wave * 16 + c] = acc[c];
  __syncthreads();
  #pragma unroll
  for (int i = 0; i < 16; i++) {
    int r = wave * 16 + i;
    atomicAdd(delta + r * 1024 + col0 + lane, xs[r * 65 + lane]);
  }
}

// ---- kernel D: out = LayerNorm(x + delta), one wave per row ---------------
__global__ __launch_bounds__(256, 4) void ln_kernel(
    const float4* __restrict__ x4, const float4* __restrict__ delta4,
    const float4* __restrict__ g4, const float4* __restrict__ b4,
    float4* __restrict__ out4) {
  const int tid = threadIdx.x;
  const int wave = tid >> 6, lane = tid & 63;
  const int row = blockIdx.x * 4 + wave;       // 0..4095
  const int b = row >> 11, s = row & 2047;

  float4 v[4];
  #pragma unroll
  for (int i = 0; i < 4; i++) v[i] = x4[row * 256 + i * 64 + lane];
  if (s >= 2016) {                             // wave-uniform branch
    int drow = b * 32 + (s - 2016);
    #pragma unroll
    for (int i = 0; i < 4; i++) {
      float4 d = delta4[drow * 256 + i * 64 + lane];
      v[i].x += d.x; v[i].y += d.y; v[i].z += d.z; v[i].w += d.w;
    }
  }
  float sum = 0.f, ss = 0.f;
  #pragma unroll
  for (int i = 0; i < 4; i++) {
    sum += v[i].x + v[i].y + v[i].z + v[i].w;
    ss  += v[i].x * v[i].x + v[i].y * v[i].y + v[i].z * v[i].z + v[i].w * v[i].w;
  }
  #pragma unroll
  for (int off = 1; off < 64; off <<= 1) {
    sum += __shfl_xor(sum, off);
    ss  += __shfl_xor(ss, off);
  }
  float mu   = sum * (1.f / 1024.f);
  float var  = ss * (1.f / 1024.f) - mu * mu;
  float rstd = rsqrtf(var + 1e-5f);

  #pragma unroll
  for (int i = 0; i < 4; i++) {
    float4 g = g4[i * 64 + lane];
    float4 be = b4[i * 64 + lane];
    float4 o;
    o.x = (v[i].x - mu) * rstd * g.x + be.x;
    o.y = (v[i].y - mu) * rstd * g.y + be.y;
    o.z = (v[i].z - mu) * rstd * g.z + be.z;
    o.w = (v[i].w - mu) * rstd * g.w + be.w;
    out4[row * 256 + i * 64 + lane] = o;
  }
}

// ---------------------------------------------------------------------------
extern "C" void kernel_launch(void* const* d_in, const int* in_sizes, int n_in,
                              void* d_out, int out_size, void* d_ws, size_t ws_size,
                              hipStream_t stream) {
  const float* x   = (const float*)d_in[0];
  const float* Wq  = (const float*)d_in[1];
  const float* Wk  = (const float*)d_in[2];
  const float* Wv  = (const float*)d_in[3];  // NB: dict order, W_V before W_Kp
  const float* Wkp = (const float*)d_in[4];
  const float* Wo  = (const float*)d_in[5];
  const float* gam = (const float*)d_in[6];
  const float* bet = (const float*)d_in[7];
  float* out = (float*)d_out;
  float* ws  = (float*)d_ws;   // needs 1.5 MB

  hipLaunchKernelGGL(zero_ws, dim3(WS_FLOATS / 1024), dim3(256), 0, stream,
                     (float4*)ws);
  hipLaunchKernelGGL(proj_kernel, dim3(64, 16), dim3(256), 0, stream,
                     x, Wq, Wk, Wkp, Wv, ws);
  hipLaunchKernelGGL(attn_kernel, dim3(8, 16, 2), dim3(256), 0, stream,
                     ws, ws + Z_OFF);
  hipLaunchKernelGGL(wo_kernel, dim3(16, 32), dim3(256), 0, stream,
                     ws + Z_OFF, Wo, ws + DELTA_OFF);
  hipLaunchKernelGGL(ln_kernel, dim3(1024), dim3(256), 0, stream,
                     (const float4*)x, (const float4*)(ws + DELTA_OFF),
                     (const float4*)gam, (const float4*)bet, (float4*)out);
}